// Round 19
// baseline (182.815 us; speedup 1.0000x reference)
//
#include <hip/hip_runtime.h>
#include <hip/hip_bf16.h>
#include <hip/hip_cooperative_groups.h>
#include <math.h>
#include <stdint.h>

#define N_TOKENS 16384
#define DIM 4096
#define NEXP 64

namespace cg = cooperative_groups;

typedef const __attribute__((address_space(1))) void gvoid_t;
typedef __attribute__((address_space(3))) void svoid_t;
typedef short bf16x8 __attribute__((ext_vector_type(8)));
typedef float f32x4 __attribute__((ext_vector_type(4)));

constexpr int TOK_BLK = 32;  // tokens per block -> grid 512 (2 blocks/CU)

__device__ __forceinline__ unsigned short bf16_rn(float f) {
  unsigned u = __float_as_uint(f);
  u += 0x7fffu + ((u >> 16) & 1u);
  return (unsigned short)(u >> 16);
}
__device__ __forceinline__ float bf16_tof(unsigned short h) {
  return __uint_as_float(((unsigned)h) << 16);
}

// packed hi/lo split: 8 floats -> bf16x8 hi + bf16x8 lo via v_cvt_pk_bf16_f32
__device__ __forceinline__ void split8(const float4 a, const float4 b,
                                       bf16x8& hi, bf16x8& lo) {
  const float f[8] = {a.x, a.y, a.z, a.w, b.x, b.y, b.z, b.w};
  union { unsigned u[4]; bf16x8 v; } H, L;
#pragma unroll
  for (int p = 0; p < 4; ++p) {
    const float2 fp = make_float2(f[2 * p], f[2 * p + 1]);
    const __hip_bfloat162 hh = __float22bfloat162_rn(fp);
    const unsigned uh = *(const unsigned*)&hh;
    const float h0 = __uint_as_float(uh << 16);
    const float h1 = __uint_as_float(uh & 0xffff0000u);
    const __hip_bfloat162 ll =
        __float22bfloat162_rn(make_float2(fp.x - h0, fp.y - h1));
    H.u[p] = uh;
    L.u[p] = *(const unsigned*)&ll;
  }
  hi = H.v;
  lo = L.v;
}

// ---- mono cooperative kernel: Wsplit | sync | GEMM+softmax+top2 | sync | sort
// Phase B is the R16-verbatim T3/T4 2-phase pipeline (94.7us proven):
//   stage(t+1) [6 glds] ; s_waitcnt vmcnt(6) (waits chunk t ONLY, t+1 stays in
//   flight across the barrier) ; s_barrier ; compute(t) ; s_barrier.
// R18 lesson applied: W hi/lo PRE-SPLIT in phase A (in-register split inside
// the barrier-locked compute phase cost ~30us). Cooperative launch removes
// 2 dispatch boundaries + the memset dispatch (~8-12us).
__global__ __launch_bounds__(256, 2) void mono(
    const float* __restrict__ x, const float* __restrict__ W,
    float* __restrict__ out, int* __restrict__ sel, int* __restrict__ cnt,
    unsigned short* __restrict__ Whi, unsigned short* __restrict__ Wlo) {
  __shared__ __align__(16) unsigned char smem[49408];
  float* const x0 = (float*)smem;                               // 8 KB
  float* const x1 = (float*)(smem + 8192);                      // 8 KB
  unsigned short* const wh0 = (unsigned short*)(smem + 16384);  // 8 KB
  unsigned short* const wl0 = (unsigned short*)(smem + 24576);  // 8 KB
  unsigned short* const wh1 = (unsigned short*)(smem + 32768);  // 8 KB
  unsigned short* const wl1 = (unsigned short*)(smem + 40960);  // 8 KB
  float* const lg = (float*)smem;          // overlay after K-loop (8.7 KB)
  int* const hist = (int*)(smem + 49152);  // 256 B

  const int tid = threadIdx.x;
  const int bid = blockIdx.x;
  const int lane = tid & 63;
  const int wid = __builtin_amdgcn_readfirstlane(tid >> 6);  // wave 0..3

  // ---------------- phase A: W hi/lo split + cnt zero ----------------
  if (bid < 256) {
    const int i = (bid * 256 + tid) * 4;
    const float4 f = *(const float4*)(W + i);
    ushort4 h, l;
    h.x = bf16_rn(f.x); l.x = bf16_rn(f.x - bf16_tof(h.x));
    h.y = bf16_rn(f.y); l.y = bf16_rn(f.y - bf16_tof(h.y));
    h.z = bf16_rn(f.z); l.z = bf16_rn(f.z - bf16_tof(h.z));
    h.w = bf16_rn(f.w); l.w = bf16_rn(f.w - bf16_tof(h.w));
    *(ushort4*)(Whi + i) = h;
    *(ushort4*)(Wlo + i) = l;
  } else if (bid < 264) {
    ((int4*)cnt)[(bid - 256) * 256 + tid] = make_int4(0, 0, 0, 0);
  }
  cg::this_grid().sync();

  // ---------------- phase B: pipelined GEMM + softmax + top2 + hist ----------
  const int th = wid & 1;   // token half
  const int eh = wid >> 1;  // expert half
  const int r = lane & 15;  // A token row / B expert col within tile
  const int g = lane >> 4;  // k-group
  const int tok0 = bid * TOK_BLK;
  float* const topw = out;

  f32x4 acc[2] = {};  // 2 N-tiles

  auto stage = [&](float* xd, unsigned short* whd, unsigned short* wld,
                   int kc) {
#pragma unroll
    for (int q = 0; q < 2; ++q) {  // x: 4 rows x 16 slots per glds
      const int r0 = wid * 8 + q * 4;
      const int row = r0 + (lane >> 4);
      const float* src =
          x + (size_t)(tok0 + row) * DIM + kc + 4 * ((lane & 15) ^ (row & 15));
      __builtin_amdgcn_global_load_lds((gvoid_t*)src, (svoid_t*)(xd + r0 * 64),
                                       16, 0, 0);
    }
#pragma unroll
    for (int q = 0; q < 2; ++q) {  // W: 8 rows x 8 slots per glds, hi+lo
      const int r0 = wid * 16 + q * 8;
      const int row = r0 + (lane >> 3);
      const int s = (lane & 7) ^ (row & 7);
      __builtin_amdgcn_global_load_lds(
          (gvoid_t*)(Whi + (size_t)row * DIM + kc + 8 * s),
          (svoid_t*)(whd + r0 * 64), 16, 0, 0);
      __builtin_amdgcn_global_load_lds(
          (gvoid_t*)(Wlo + (size_t)row * DIM + kc + 8 * s),
          (svoid_t*)(wld + r0 * 64), 16, 0, 0);
    }
  };

  auto compute = [&](const float* xb, const unsigned short* whb,
                     const unsigned short* wlb) {
    const int xrow = th * 16 + r;
#pragma unroll
    for (int h = 0; h < 2; ++h) {
      const int s0 = h * 8 + 2 * g;
      const float4 fa = *(const float4*)(xb + xrow * 64 + 4 * (s0 ^ (xrow & 15)));
      const float4 fb =
          *(const float4*)(xb + xrow * 64 + 4 * ((s0 + 1) ^ (xrow & 15)));
      bf16x8 Ahi, Alo;
      split8(fa, fb, Ahi, Alo);
#pragma unroll
      for (int nt = 0; nt < 2; ++nt) {
        const int wrow = eh * 32 + nt * 16 + r;
        const int wadr = wrow * 64 + 8 * ((h * 4 + g) ^ (wrow & 7));
        const bf16x8 Bhi = *(const bf16x8*)(whb + wadr);
        const bf16x8 Blo = *(const bf16x8*)(wlb + wadr);
        acc[nt] = __builtin_amdgcn_mfma_f32_16x16x32_bf16(Ahi, Bhi, acc[nt], 0, 0, 0);
        acc[nt] = __builtin_amdgcn_mfma_f32_16x16x32_bf16(Alo, Bhi, acc[nt], 0, 0, 0);
        acc[nt] = __builtin_amdgcn_mfma_f32_16x16x32_bf16(Ahi, Blo, acc[nt], 0, 0, 0);
      }
    }
  };

  stage(x0, wh0, wl0, 0);
  for (int t = 0; t < 64; t += 2) {
    if (t + 1 < 64) {
      stage(x1, wh1, wl1, (t + 1) * 64);
      asm volatile("s_waitcnt vmcnt(6)" ::: "memory");  // stage(t) landed
    } else {
      asm volatile("s_waitcnt vmcnt(0)" ::: "memory");
    }
    __builtin_amdgcn_sched_barrier(0);
    __builtin_amdgcn_s_barrier();
    compute(x0, wh0, wl0);
    __builtin_amdgcn_s_barrier();
    __builtin_amdgcn_sched_barrier(0);
    if (t + 2 < 64) {
      stage(x0, wh0, wl0, (t + 2) * 64);
      asm volatile("s_waitcnt vmcnt(6)" ::: "memory");  // stage(t+1) landed
    } else {
      asm volatile("s_waitcnt vmcnt(0)" ::: "memory");
    }
    __builtin_amdgcn_sched_barrier(0);
    __builtin_amdgcn_s_barrier();
    compute(x1, wh1, wl1);
    __builtin_amdgcn_s_barrier();
    __builtin_amdgcn_sched_barrier(0);
  }

  if (tid < NEXP) hist[tid] = 0;
#pragma unroll
  for (int nt = 0; nt < 2; ++nt)
#pragma unroll
    for (int rg = 0; rg < 4; ++rg)
      lg[(th * 16 + g * 4 + rg) * 68 + eh * 32 + nt * 16 + r] = acc[nt][rg];
  __syncthreads();

  if (tid < TOK_BLK) {
    const float* rowp = lg + tid * 68;
    float4 v[16];
#pragma unroll
    for (int c = 0; c < 16; ++c) v[c] = *(const float4*)(rowp + c * 4);

    float v0 = -INFINITY, v1 = -INFINITY;
    int i0 = 0, i1 = 0;
#define TOP2_STEP(val, idx)                                  \
  {                                                          \
    const float vv = (val);                                  \
    const int ee = (idx);                                    \
    if (vv > v0) { v1 = v0; i1 = i0; v0 = vv; i0 = ee; }     \
    else if (vv > v1) { v1 = vv; i1 = ee; }                  \
  }
#pragma unroll
    for (int c = 0; c < 16; ++c) {
      TOP2_STEP(v[c].x, c * 4 + 0);
      TOP2_STEP(v[c].y, c * 4 + 1);
      TOP2_STEP(v[c].z, c * 4 + 2);
      TOP2_STEP(v[c].w, c * 4 + 3);
    }
#undef TOP2_STEP

    float denom = 0.f;
#pragma unroll
    for (int c = 0; c < 16; ++c) {
      denom += expf(v[c].x - v0);
      denom += expf(v[c].y - v0);
      denom += expf(v[c].z - v0);
      denom += expf(v[c].w - v0);
    }
    const float w0s = 1.0f / denom;  // expf(0)==1 exactly
    const float w1s = expf(v1 - v0) / denom;

    const int tk = tok0 + tid;
    topw[2 * tk + 0] = w0s;
    topw[2 * tk + 1] = w1s;
    sel[2 * tk + 0] = i0;
    sel[2 * tk + 1] = i1;
    atomicAdd(&hist[i0], 1);
    atomicAdd(&hist[i1], 1);
  }
  __syncthreads();
  if (tid < NEXP) {
    const int h = hist[tid];
    if (h) atomicAdd(&cnt[tid * 128 + (bid >> 2)], h);  // cnt[e][chunk]
  }
  cg::this_grid().sync();

  // ---------------- phase C: merged scan + stable scatter (blocks 0..127) ----
  if (bid < 128) {
    int* const tot = (int*)smem;                 // 256 B
    int* const parts = (int*)(smem + 256);       // 256 B
    int* const cbs = (int*)(smem + 512);         // 256 B
    int* const wcnt = (int*)(smem + 768);        // 1 KB
    const int b = bid;
    const int s = b * 256 + tid;
    const int e = sel[s];
    const int wv = tid >> 6;
    wcnt[tid] = 0;

    if (tid < NEXP) {
      const int4* row4 = (const int4*)(cnt + tid * 128);
      int run = 0, part = 0;
#pragma unroll
      for (int q = 0; q < 32; ++q) {
        const int4 v = row4[q];
        if (4 * q + 0 < b) part += v.x;
        if (4 * q + 1 < b) part += v.y;
        if (4 * q + 2 < b) part += v.z;
        if (4 * q + 3 < b) part += v.w;
        run += v.x + v.y + v.z + v.w;
      }
      tot[tid] = run;
      parts[tid] = part;
      if (b == 0) out[4 * N_TOKENS + tid] = (float)run;  // counts output
    }
    __syncthreads();
    if (tid < NEXP) {
      int g2 = 0;
      for (int q = 0; q < tid; ++q) g2 += tot[q];
      cbs[tid] = g2 + parts[tid];
    }

    unsigned long long mask = ~0ull;
#pragma unroll
    for (int bb = 0; bb < 6; ++bb) {
      const unsigned long long bl = __ballot((e >> bb) & 1);
      mask &= ((e >> bb) & 1) ? bl : ~bl;
    }
    const unsigned long long below = mask & ((1ull << lane) - 1ull);
    const int wr = __popcll(below);
    if (wr == 0) wcnt[wv * NEXP + e] = __popcll(mask);
    __syncthreads();

    int base = cbs[e];
    for (int w2 = 0; w2 < wv; ++w2) base += wcnt[w2 * NEXP + e];
    out[2 * N_TOKENS + base + wr] = (float)s;  // gather_indices output
  }
}

extern "C" void kernel_launch(void* const* d_in, const int* in_sizes, int n_in,
                              void* d_out, int out_size, void* d_ws, size_t ws_size,
                              hipStream_t stream) {
  const float* x = (const float*)d_in[0];
  const float* W = (const float*)d_in[1];
  float* out = (float*)d_out;

  unsigned short* whi_g = (unsigned short*)d_ws;  // 512 KB
  unsigned short* wlo_g = whi_g + NEXP * DIM;     // 512 KB
  int* sel = (int*)(wlo_g + NEXP * DIM);          // 128 KB
  int* cnt = sel + N_TOKENS * 2;                  // 32 KB (cnt[e][128])

  void* args[] = {(void*)&x, (void*)&W, (void*)&out, (void*)&sel,
                  (void*)&cnt, (void*)&whi_g, (void*)&wlo_g};
  hipLaunchCooperativeKernel((const void*)mono, dim3(N_TOKENS / TOK_BLK),
                             dim3(256), args, 0, stream);
}